// Round 16
// baseline (65.621 us; speedup 1.0000x reference)
//
#include <hip/hip_runtime.h>

#define N_NODES 50000
#define N_EDGES 100000
#define NUM_RELS 200
#define DIM 64
#define CAP 512
#define TILES 4            // 128 entries per msg block (2 sub-tiles of 64)
#define KPAD 72            // padded K-stride in ushorts (144B): balanced banks, 16B aligned

typedef __attribute__((ext_vector_type(8))) short bf16x8;
typedef __attribute__((ext_vector_type(8))) unsigned short u16x8;
typedef __attribute__((ext_vector_type(4))) float f32x4;

// ---- workspace layout ----
// int32 region: last[50000] ++ cur[208] ++ bn[200*512] ++ bs[200*512]
#define OFF_LAST 0
#define OFF_CUR  50000           // raw counters, init -1 via 0xFF fill; logical = raw+1
#define OFF_BN   50208
#define OFF_BS   152608
// byte offsets (16B aligned):
#define HB_OFF   1020032u        // bf16 h: 50000*64 ushorts = 6.4 MB
#define WT_OFF   7420032u        // bf16 W^T (K-major): 201*64*64 ushorts (wself = idx 200)

__device__ __forceinline__ unsigned short f2bf(float x) {
    union { float f; unsigned u; } v; v.f = x;
    unsigned r = v.u + 0x7FFFu + ((v.u >> 16) & 1u);   // RNE
    return (unsigned short)(r >> 16);
}

// ---------- K1: edge_max + W transpose/convert + h convert (init via memset) ----------
#define T_EM 391                 // ceil(100000/256)
#define T_WT 201                 // 200 rels + wself
#define T_HC 391                 // 8192 floats per task

__global__ __launch_bounds__(256) void prep_kernel(
    const float* __restrict__ h, const float* __restrict__ weight,
    const float* __restrict__ wself, const int* __restrict__ edges,
    int* __restrict__ ws, unsigned short* __restrict__ hb,
    unsigned short* __restrict__ wt)
{
    __shared__ float Wl[DIM * DIM];
    int b = blockIdx.x, t = threadIdx.x;

    if (b < T_EM) {
        int e = b * 256 + t;
        if (e < N_EDGES) atomicMax(&ws[OFF_LAST + edges[e * 3 + 2]], e);
        return;
    }
    if (b < T_EM + T_WT) {
        int rel = b - T_EM;
        const float* src = (rel < NUM_RELS) ? (weight + (size_t)rel * DIM * DIM) : wself;
#pragma unroll
        for (int j = 0; j < 16; ++j) Wl[t + j * 256] = src[t + j * 256];
        __syncthreads();
        int cc = t >> 2, q = t & 3;          // out-col, k-quarter
        unsigned short tmp[16];
#pragma unroll
        for (int kk = 0; kk < 16; ++kk)
            tmp[kk] = f2bf(Wl[(q * 16 + kk) * DIM + cc]);
        unsigned short* dst = wt + (size_t)rel * DIM * DIM + cc * DIM + q * 16;
        *(u16x8*)dst       = *(const u16x8*)&tmp[0];
        *(u16x8*)(dst + 8) = *(const u16x8*)&tmp[8];
        return;
    }
    {
        long off = (long)(b - T_EM - T_WT) * 8192 + (long)t * 32;
        if (off < (long)N_NODES * DIM) {
#pragma unroll
            for (int half = 0; half < 2; ++half) {
                const float4* src = (const float4*)(h + off + half * 16);
                unsigned short tmp[16];
#pragma unroll
                for (int j = 0; j < 4; ++j) {
                    float4 v = src[j];
                    tmp[j*4+0]=f2bf(v.x); tmp[j*4+1]=f2bf(v.y);
                    tmp[j*4+2]=f2bf(v.z); tmp[j*4+3]=f2bf(v.w);
                }
                *(u16x8*)(hb + off + half * 16)     = *(const u16x8*)&tmp[0];
                *(u16x8*)(hb + off + half * 16 + 8) = *(const u16x8*)&tmp[8];
            }
        }
    }
}

// ---------- K2: bucket + self GEMM (128 nodes/block, direct-A, W in LDS) ----------
#define BK_BLKS 196              // ceil(50000/256)
#define SELF_TILES 391           // ceil(50000/128)

__global__ __launch_bounds__(256) void bucket_self_kernel(
    const int* __restrict__ edges, const unsigned short* __restrict__ hb,
    const unsigned short* __restrict__ wt, int* __restrict__ ws,
    float* __restrict__ out)
{
    __shared__ unsigned short Wsh[DIM * KPAD];
    int t = threadIdx.x;

    if (blockIdx.x < BK_BLKS) {
        int n = blockIdx.x * 256 + t;
        if (n < N_NODES) {
            int li = ws[OFF_LAST + n];
            if (li >= 0) {
                int r = edges[li * 3 + 1];
                int s = edges[li * 3 + 0];
                int pos = atomicAdd(&ws[OFF_CUR + r], 1) + 1;   // raw starts at -1
                if (pos < CAP) {
                    ws[OFF_BN + r * CAP + pos] = n;
                    ws[OFF_BS + r * CAP + pos] = s;
                }
            }
        }
        return;
    }

    int base = (blockIdx.x - BK_BLKS) * 128;
    int l = t & 63;
    int w = __builtin_amdgcn_readfirstlane(t >> 6);
    int r16 = l & 15, kb = l >> 4;

    // direct A-frag loads for both sub-tiles (issued before W stage)
    int ar0 = base + w * 16 + r16;        if (ar0 >= N_NODES) ar0 = N_NODES - 1;
    int ar1 = base + 64 + w * 16 + r16;   if (ar1 >= N_NODES) ar1 = N_NODES - 1;
    const unsigned short* ap0 = hb + (size_t)ar0 * DIM + kb * 8;
    const unsigned short* ap1 = hb + (size_t)ar1 * DIM + kb * 8;
    bf16x8 a0 = *(const bf16x8*)ap0;
    bf16x8 a1 = *(const bf16x8*)(ap0 + 32);
    bf16x8 a2 = *(const bf16x8*)ap1;
    bf16x8 a3 = *(const bf16x8*)(ap1 + 32);

    {   // stage W_self
        int row = t >> 2, q = t & 3;
        const unsigned short* wsrc = wt + (size_t)NUM_RELS * DIM * DIM + row * DIM + q * 16;
        *(u16x8*)&Wsh[row * KPAD + q * 16]     = *(const u16x8*)wsrc;
        *(u16x8*)&Wsh[row * KPAD + q * 16 + 8] = *(const u16x8*)(wsrc + 8);
    }
    __syncthreads();

#pragma unroll
    for (int sub = 0; sub < 2; ++sub) {
        bf16x8 aa0 = sub ? a2 : a0;
        bf16x8 aa1 = sub ? a3 : a1;
        int sbase = base + sub * 64;
        if (sbase >= N_NODES) break;
#pragma unroll
        for (int n4 = 0; n4 < 4; ++n4) {
            bf16x8 b0 = *(const bf16x8*)&Wsh[(n4 * 16 + r16) * KPAD + kb * 8];
            bf16x8 b1 = *(const bf16x8*)&Wsh[(n4 * 16 + r16) * KPAD + 32 + kb * 8];
            f32x4 acc = {0.f, 0.f, 0.f, 0.f};
            acc = __builtin_amdgcn_mfma_f32_16x16x32_bf16(aa0, b0, acc, 0, 0, 0);
            acc = __builtin_amdgcn_mfma_f32_16x16x32_bf16(aa1, b1, acc, 0, 0, 0);
#pragma unroll
            for (int r = 0; r < 4; ++r) {
                int nn = sbase + w * 16 + kb * 4 + r;     // C row = (l>>4)*4 + r
                if (nn < N_NODES) out[(size_t)nn * DIM + n4 * 16 + r16] = acc[r];
            }
        }
    }
}

// ---------- K3: msg GEMM (128 entries/block, direct-A, W in LDS) ----------
__global__ __launch_bounds__(256) void msg_kernel(
    const unsigned short* __restrict__ hb, const unsigned short* __restrict__ wt,
    const int* __restrict__ ws, float* __restrict__ out)
{
    __shared__ unsigned short Wsh[DIM * KPAD];

    int rel = blockIdx.x >> 2;
    int tile = blockIdx.x & 3;
    int c = ws[OFF_CUR + rel] + 1;                    // logical count (raw+1)
    if (c > CAP) c = CAP;
    int start = tile * 128;
    if (start >= c) return;

    int t = threadIdx.x;
    int l = t & 63;
    int w = __builtin_amdgcn_readfirstlane(t >> 6);
    int r16 = l & 15, kb = l >> 4;
    const int* bn = ws + OFF_BN + rel * CAP;
    const int* bs = ws + OFF_BS + rel * CAP;
    bool has1 = (start + 64) < c;                     // block-uniform

    // sub-tile 0 A-frags (gather issued before W stage)
    int pa0 = start + w * 16 + r16; if (pa0 >= c) pa0 = c - 1;
    int s0 = bs[pa0];
    const unsigned short* ap0 = hb + (size_t)s0 * DIM + kb * 8;
    bf16x8 a0 = *(const bf16x8*)ap0;
    bf16x8 a1 = *(const bf16x8*)(ap0 + 32);

    bf16x8 a2, a3;
    if (has1) {
        int pa1 = start + 64 + w * 16 + r16; if (pa1 >= c) pa1 = c - 1;
        int s1 = bs[pa1];
        const unsigned short* ap1 = hb + (size_t)s1 * DIM + kb * 8;
        a2 = *(const bf16x8*)ap1;
        a3 = *(const bf16x8*)(ap1 + 32);
    }

    {   // stage W_rel
        int row = t >> 2, q = t & 3;
        const unsigned short* wsrc = wt + (size_t)rel * DIM * DIM + row * DIM + q * 16;
        *(u16x8*)&Wsh[row * KPAD + q * 16]     = *(const u16x8*)wsrc;
        *(u16x8*)&Wsh[row * KPAD + q * 16 + 8] = *(const u16x8*)(wsrc + 8);
    }
    __syncthreads();

    int nsub = has1 ? 2 : 1;
    for (int sub = 0; sub < nsub; ++sub) {
        bf16x8 aa0 = sub ? a2 : a0;
        bf16x8 aa1 = sub ? a3 : a1;
        int sbase = start + sub * 64;

        int nn[4]; bool vv[4];
#pragma unroll
        for (int r = 0; r < 4; ++r) {
            int p = sbase + w * 16 + kb * 4 + r;
            vv[r] = p < c;
            nn[r] = bn[vv[r] ? p : 0];
        }
#pragma unroll
        for (int n4 = 0; n4 < 4; ++n4) {
            bf16x8 b0 = *(const bf16x8*)&Wsh[(n4 * 16 + r16) * KPAD + kb * 8];
            bf16x8 b1 = *(const bf16x8*)&Wsh[(n4 * 16 + r16) * KPAD + 32 + kb * 8];
            f32x4 acc = {0.f, 0.f, 0.f, 0.f};
            acc = __builtin_amdgcn_mfma_f32_16x16x32_bf16(aa0, b0, acc, 0, 0, 0);
            acc = __builtin_amdgcn_mfma_f32_16x16x32_bf16(aa1, b1, acc, 0, 0, 0);
#pragma unroll
            for (int r = 0; r < 4; ++r)
                if (vv[r]) out[(size_t)nn[r] * DIM + n4 * 16 + r16] += acc[r];
        }
    }
}

extern "C" void kernel_launch(void* const* d_in, const int* in_sizes, int n_in,
                              void* d_out, int out_size, void* d_ws, size_t ws_size,
                              hipStream_t stream) {
    const float* h      = (const float*)d_in[0];
    const int*   edges  = (const int*)d_in[1];
    const float* weight = (const float*)d_in[2];
    const float* wself  = (const float*)d_in[3];
    float* out = (float*)d_out;
    int* wsi = (int*)d_ws;
    unsigned short* hb = (unsigned short*)((char*)d_ws + HB_OFF);
    unsigned short* wt = (unsigned short*)((char*)d_ws + WT_OFF);

    // single fill: last = -1 AND raw counters = -1
    hipMemsetAsync(d_ws, 0xFF, (size_t)(N_NODES + 208) * 4, stream);

    prep_kernel<<<T_EM + T_WT + T_HC, 256, 0, stream>>>(h, weight, wself, edges, wsi, hb, wt);
    bucket_self_kernel<<<BK_BLKS + SELF_TILES, 256, 0, stream>>>(edges, hb, wt, wsi, out);
    msg_kernel<<<NUM_RELS * TILES, 256, 0, stream>>>(hb, wt, wsi, out);
}